// Round 5
// baseline (78617.865 us; speedup 1.0000x reference)
//
#include <hip/hip_runtime.h>
#include <stdint.h>

#define L4   250   // chase chunk length
#define GRP  50    // chunks per map-composition group
#define PF   32    // feat prefetch depth in k_chain
#define CSZ  256   // checkpoint interval (power of 2)
#define CSB  8     // log2(CSZ)

// DPP row_ror:K — dst lane i reads src lane (i-K)&15 within its row of 16.
// Direction HW-validated bit-exact (absmax 0) in prior rounds.
template<int K>
__device__ __forceinline__ float rotr(float x) {
  return __int_as_float(__builtin_amdgcn_mov_dpp(__float_as_int(x), 0x120 + K, 0xF, 0xF, false));
}

// Full 16-candidate exact step. Lane layout: n = lane&15, lane holds fv[n];
// trr[k] = tr[n][(n-k)&15]. c_k = fv[(n-k)&15] + tr[n][(n-k)&15] covers every
// p exactly once. fp32 max over 16 finite values is order-independent ->
// bit-identical to the reference's jnp.max regardless of tree shape.
// Depth-optimized: only ONE cross-lane hop on the dependency path (the first
// add_dpp); tree is 3 max3 levels; late-issued c15 enters at level 2 so its
// late ready-time doesn't extend the root.
__device__ __forceinline__ float vstep(float fv, const float* __restrict__ trr) {
  float c0  = fv           + trr[0];
  float c1  = rotr<1 >(fv) + trr[1];
  float c2  = rotr<2 >(fv) + trr[2];
  float c3  = rotr<3 >(fv) + trr[3];
  float c4  = rotr<4 >(fv) + trr[4];
  float c5  = rotr<5 >(fv) + trr[5];
  float c6  = rotr<6 >(fv) + trr[6];
  float c7  = rotr<7 >(fv) + trr[7];
  float c8  = rotr<8 >(fv) + trr[8];
  float c9  = rotr<9 >(fv) + trr[9];
  float c10 = rotr<10>(fv) + trr[10];
  float c11 = rotr<11>(fv) + trr[11];
  float c12 = rotr<12>(fv) + trr[12];
  float c13 = rotr<13>(fv) + trr[13];
  float c14 = rotr<14>(fv) + trr[14];
  float c15 = rotr<15>(fv) + trr[15];
  float t0 = fmaxf(fmaxf(c0,  c1),  c2);   // v_max3
  float t1 = fmaxf(fmaxf(c3,  c4),  c5);
  float t2 = fmaxf(fmaxf(c6,  c7),  c8);
  float t3 = fmaxf(fmaxf(c9,  c10), c11);
  float t4 = fmaxf(fmaxf(c12, c13), c14);
  float u0 = fmaxf(fmaxf(t0, t1), t2);
  float u1 = fmaxf(fmaxf(t3, t4), c15);    // c15 enters shallow
  return fmaxf(u0, u1);
}

// ---------------------------------------------------------------------------
// K1: value-only exact Viterbi forward chain. ONE wave, depth-5 critical path
// (add_dpp -> max3 -> max3 -> max -> feat add), one cross-lane hop per step.
// All 64 lanes replicate the 16-tag state (rows of 16 identical).
// Clamp-free prefetch: main loop runs to Tm <= T-PF; uniform block pointer +
// compile-time offsets -> one imm-offset global_load_dword per step.
// Stores a 64B checkpoint every CSZ steps; k_fv regenerates FV in parallel.
// ---------------------------------------------------------------------------
__global__ __launch_bounds__(64)
void k_chain(const float* __restrict__ feats, const float* __restrict__ trans,
             float* __restrict__ CKPT, int* __restrict__ last_tag, int T) {
  const int l = threadIdx.x;
  const int n = l & 15;

  float trr[16];
  #pragma unroll
  for (int k = 0; k < 16; ++k) trr[k] = trans[n * 16 + ((n - k) & 15)];

  float fv = 0.0f; // fv[n] = 0 initially

  float fbuf[PF];
  #pragma unroll
  for (int i = 0; i < PF; ++i) {
    int idx = i < T ? i : (T - 1);
    fbuf[i] = feats[(size_t)idx * 16 + n];
  }

  int t = 0;
  const int Tm = (T >= 2 * PF) ? ((T - PF) & ~(PF - 1)) : 0;
  for (; t < Tm; t += PF) {
    if ((t & (CSZ - 1)) == 0) CKPT[(size_t)(t >> CSB) * 16 + n] = fv;
    const float* __restrict__ pf_ptr = feats + (size_t)(t + PF) * 16; // uniform
    #pragma unroll
    for (int u = 0; u < PF; ++u) {
      fv = vstep(fv, trr) + fbuf[u];
      fbuf[u] = pf_ptr[u * 16 + n];   // imm-offset load, never OOB (t+u+PF <= T-1)
    }
  }
  for (; t < T; ++t) { // tail (< 2*PF steps): direct loads, cache-hot lines
    if ((t & (CSZ - 1)) == 0) CKPT[(size_t)(t >> CSB) * 16 + n] = fv;
    fv = vstep(fv, trr) + feats[(size_t)t * 16 + n];
  }

  // last_tag = argmax of final fv (first-index tie-break, ascending p).
  // Lanes 0-15 hold fv[n].
  float bv = __shfl(fv, 0, 64); int bi = 0;
  #pragma unroll
  for (int p = 1; p < 16; ++p) {
    float ov = __shfl(fv, p, 64);
    if (ov > bv) { bv = ov; bi = p; }
  }
  if (l == 0) *last_tag = bi;
}

// ---------------------------------------------------------------------------
// K1b: parallel FV regeneration. One wave per CSZ-step chunk; replays the
// identical fp32 recurrence from the chunk's checkpoint -> bit-exact FV.
// Throughput-bound (thousands of independent waves).
// ---------------------------------------------------------------------------
__global__ __launch_bounds__(256)
void k_fv(const float* __restrict__ CKPT, const float* __restrict__ trans,
          const float* __restrict__ feats, float* __restrict__ FV, int T, int NC) {
  const int tid = threadIdx.x;
  const int wid = blockIdx.x * 4 + (tid >> 6);
  const int l = tid & 63;
  const int n = l & 15;
  if (wid >= NC) return;

  float trr[16];
  #pragma unroll
  for (int k = 0; k < 16; ++k) trr[k] = trans[n * 16 + ((n - k) & 15)];

  float fv = CKPT[(size_t)wid * 16 + n];
  const int a = wid * CSZ;
  int b = a + CSZ; if (b > T) b = T;
  for (int t = a; t < b; ++t) {
    FV[(size_t)t * 16 + n] = fv;            // FV[t] = fv entering step t
    fv = vstep(fv, trr) + feats[(size_t)t * 16 + n];
  }
}

// ---------------------------------------------------------------------------
// K2: parallel backpointer recompute. Thread per t.
// bp[t][n] = argmax_p fl(FV[t][p] + tr[n][p]), strict-> scan (first-max),
// bit-identical to the reference's jnp.argmax(scores, axis=1).
// ---------------------------------------------------------------------------
__global__ __launch_bounds__(256)
void k_bp(const float* __restrict__ FV, const float* __restrict__ trans,
          uint4* __restrict__ bp, int T) {
  __shared__ float str[256];
  const int tid = threadIdx.x;
  str[tid] = trans[tid];
  __syncthreads();
  const int t = blockIdx.x * blockDim.x + tid;
  if (t >= T) return;
  const float4* fr = (const float4*)(FV + (size_t)t * 16);
  float4 q0 = fr[0], q1 = fr[1], q2 = fr[2], q3 = fr[3];
  float fv[16] = {q0.x, q0.y, q0.z, q0.w, q1.x, q1.y, q1.z, q1.w,
                  q2.x, q2.y, q2.z, q2.w, q3.x, q3.y, q3.z, q3.w};
  uint32_t w[4];
  #pragma unroll
  for (int g = 0; g < 4; ++g) {
    uint32_t word = 0;
    #pragma unroll
    for (int s = 0; s < 4; ++s) {
      const int nn = 4 * g + s;
      float best = fv[0] + str[nn * 16 + 0];
      int bi = 0;
      #pragma unroll
      for (int p = 1; p < 16; ++p) {
        float v = fv[p] + str[nn * 16 + p];
        if (v > best) { best = v; bi = p; }
      }
      word |= (uint32_t)bi << (8 * s);
    }
    w[g] = word;
  }
  bp[t] = make_uint4(w[0], w[1], w[2], w[3]);
}

// ---------------------------------------------------------------------------
// K3: per-chunk 16-hypothesis backtrack (exact integer pointer chase).
// ---------------------------------------------------------------------------
__global__ __launch_bounds__(64)
void k_chase(const unsigned char* __restrict__ bp, unsigned char* __restrict__ st,
             unsigned char* __restrict__ maps, int T, int C) {
  const int tid = threadIdx.x;
  const int chunk = blockIdx.x * 4 + (tid >> 4);
  const int h = tid & 15;
  if (chunk >= C) return;
  const int a = chunk * L4;
  int b = a + L4; if (b > T) b = T;
  int cur = h;
  for (int t = b - 1; t >= a; --t) {
    cur = bp[(size_t)t * 16 + cur];
    st[(size_t)t * 16 + h] = (unsigned char)cur;
  }
  maps[chunk * 16 + h] = (unsigned char)cur;
}

// ---------------------------------------------------------------------------
// K4: compose GRP consecutive chunk maps into one super-map per group.
// ---------------------------------------------------------------------------
__global__ __launch_bounds__(64)
void k_group(const unsigned char* __restrict__ maps, unsigned char* __restrict__ sup,
             int C, int NG) {
  const int g = blockIdx.x;
  const int e = threadIdx.x;
  if (g >= NG || e >= 16) return;
  int hi = g * GRP + GRP - 1; if (hi > C - 1) hi = C - 1;
  int cur = e;
  for (int c = hi; c >= g * GRP; --c) cur = maps[c * 16 + cur];
  sup[g * 16 + e] = (unsigned char)cur;
}

// ---------------------------------------------------------------------------
// K5: resolve true tag at every chunk's end boundary.
// ---------------------------------------------------------------------------
__global__ __launch_bounds__(128)
void k_resolve(const unsigned char* __restrict__ maps, const unsigned char* __restrict__ sup,
               const int* __restrict__ last_tag, unsigned char* __restrict__ s_arr,
               int C, int NG) {
  __shared__ unsigned char Sg[4096];
  const int tid = threadIdx.x;
  if (tid == 0) {
    int cur = *last_tag;
    for (int g = NG - 1; g >= 0; --g) {
      Sg[g] = (unsigned char)cur;
      cur = sup[g * 16 + cur];
    }
  }
  __syncthreads();
  for (int g = tid; g < NG; g += blockDim.x) {
    int cur = Sg[g];
    int hi = g * GRP + GRP - 1; if (hi > C - 1) hi = C - 1;
    for (int c = hi; c >= g * GRP; --c) {
      s_arr[c] = (unsigned char)cur;
      cur = maps[c * 16 + cur];
    }
  }
}

// ---------------------------------------------------------------------------
// K6: emit out[t] = st[t*16 + s_arr[t / L4]] as int32.
// ---------------------------------------------------------------------------
__global__ void k_emit(const unsigned char* __restrict__ st,
                       const unsigned char* __restrict__ s_arr,
                       int* __restrict__ out, int T) {
  int t = blockIdx.x * blockDim.x + threadIdx.x;
  if (t < T) out[t] = (int)st[(size_t)t * 16 + s_arr[t / L4]];
}

extern "C" void kernel_launch(void* const* d_in, const int* in_sizes, int n_in,
                              void* d_out, int out_size, void* d_ws, size_t ws_size,
                              hipStream_t stream) {
  const float* feats = (const float*)d_in[0];   // [1, T, 16] fp32
  const float* trans = (const float*)d_in[1];   // [16, 16]  fp32
  int* out = (int*)d_out;                       // [T] int32

  const int T  = in_sizes[0] / 16;
  const int C  = (T + L4 - 1) / L4;
  const int NG = (C + GRP - 1) / GRP;
  const int NC = (T + CSZ - 1) / CSZ;

  char* ws = (char*)d_ws;
  float* FV           = (float*)ws;                           // (T+1)*16 floats
  float* CKPT         = FV + (size_t)(T + 1) * 16;            // NC*16 floats
  unsigned char* bp   = (unsigned char*)(CKPT + (size_t)NC * 16); // T*16 B, 16B-aligned
  unsigned char* st   = bp + (size_t)T * 16;                  // T*16 B
  unsigned char* maps = st + (size_t)T * 16;                  // C*16
  unsigned char* sup  = maps + (size_t)C * 16;                // NG*16
  unsigned char* sarr = sup + (size_t)NG * 16;                // C
  int* last_tag = (int*)(((uintptr_t)(sarr + C) + 15) & ~(uintptr_t)15);
  size_t need = (size_t)((char*)(last_tag + 1) - ws);
  if (ws_size < need) return;  // insufficient scratch -> fail visibly

  k_chain<<<1, 64, 0, stream>>>(feats, trans, CKPT, last_tag, T);
  k_fv<<<(NC + 3) / 4, 256, 0, stream>>>(CKPT, trans, feats, FV, T, NC);
  k_bp<<<(T + 255) / 256, 256, 0, stream>>>(FV, trans, (uint4*)bp, T);
  k_chase<<<(C + 3) / 4, 64, 0, stream>>>(bp, st, maps, T, C);
  k_group<<<NG, 64, 0, stream>>>(maps, sup, C, NG);
  k_resolve<<<1, 128, 0, stream>>>(maps, sup, last_tag, sarr, C, NG);
  const int thr = 256;
  k_emit<<<(T + thr - 1) / thr, thr, 0, stream>>>(st, sarr, out, T);
}

// Round 6
// 68689.581 us; speedup vs baseline: 1.1445x; 1.1445x over previous
//
#include <hip/hip_runtime.h>
#include <stdint.h>

#define L4   250   // chase chunk length
#define GRP  50    // chunks per map-composition group
#define PF   32    // feat prefetch depth in k_chain (multiple of 4)
#define CSZ  256   // checkpoint interval (power of 2)
#define CSB  8     // log2(CSZ)

// DPP row_ror:K — dst lane i reads src lane (i-K)&15 within its row of 16.
// Direction HW-validated bit-exact (absmax 0) in prior rounds.
template<int K>
__device__ __forceinline__ float rotr(float x) {
  return __int_as_float(__builtin_amdgcn_mov_dpp(__float_as_int(x), 0x120 + K, 0xF, 0xF, false));
}

// Cross-half (lane l <-> l^32) max, VALU-speed on gfx950 via permlane32_swap.
// Feeding (m,m) and maxing both outputs yields max(m[l], m[l^32]) regardless
// of which output carries which half. HW-validated (absmax 0, rounds 3-4).
__device__ __forceinline__ float xhalf_max(float m) {
#if __has_builtin(__builtin_amdgcn_permlane32_swap)
  typedef int v2i __attribute__((ext_vector_type(2)));
  v2i r = __builtin_amdgcn_permlane32_swap(__float_as_int(m), __float_as_int(m), false, false);
  return fmaxf(__int_as_float(r[0]), __int_as_float(r[1]));
#else
  return fmaxf(m, __shfl_xor(m, 32, 64));
#endif
}

// Masked-row rotate: rows 0,1 (lanes 0-31) keep M; rows 2,3 (lanes 32-63)
// get M[(n-8)&15] = M[n^8] via row_ror:8. One v_mov_b32_dpp with
// row_mask=0xC replaces rotr<8> + cndmask. HW-validated (absmax 0, round 4).
__device__ __forceinline__ float selrot8(float M, bool hi) {
#if __has_builtin(__builtin_amdgcn_update_dpp)
  int Mi = __float_as_int(M);
  return __int_as_float(__builtin_amdgcn_update_dpp(Mi, Mi, 0x128, 0xC, 0xF, false));
#else
  float Mr = rotr<8>(M);
  return hi ? Mr : M;
#endif
}

// Full 16-candidate exact step (used by throughput kernel k_fv).
// Lane layout: n = lane&15, lane holds fv[n]; trr[k] = tr[n][(n-k)&15].
// fp32 max over 16 finite values is order-independent -> bit-identical to
// the reference's jnp.max regardless of tree shape.
__device__ __forceinline__ float vstep(float fv, const float* __restrict__ trr) {
  float c0  = fv           + trr[0];
  float c1  = rotr<1 >(fv) + trr[1];
  float c2  = rotr<2 >(fv) + trr[2];
  float c3  = rotr<3 >(fv) + trr[3];
  float c4  = rotr<4 >(fv) + trr[4];
  float c5  = rotr<5 >(fv) + trr[5];
  float c6  = rotr<6 >(fv) + trr[6];
  float c7  = rotr<7 >(fv) + trr[7];
  float c8  = rotr<8 >(fv) + trr[8];
  float c9  = rotr<9 >(fv) + trr[9];
  float c10 = rotr<10>(fv) + trr[10];
  float c11 = rotr<11>(fv) + trr[11];
  float c12 = rotr<12>(fv) + trr[12];
  float c13 = rotr<13>(fv) + trr[13];
  float c14 = rotr<14>(fv) + trr[14];
  float c15 = rotr<15>(fv) + trr[15];
  float t0 = fmaxf(fmaxf(c0,  c1),  c2);
  float t1 = fmaxf(fmaxf(c3,  c4),  c5);
  float t2 = fmaxf(fmaxf(c6,  c7),  c8);
  float t3 = fmaxf(fmaxf(c9,  c10), c11);
  float t4 = fmaxf(fmaxf(c12, c13), c14);
  float u0 = fmaxf(fmaxf(t0, t1), t2);
  float u1 = fmaxf(fmaxf(t3, t4), c15);
  return fmaxf(u0, u1);
}

// Split 8-candidate exact step (serial chain) — r4 structure, best measured
// (142 cy/step). Invariant: lane (h,n) holds fvh = fv[nid], nid = n ^ (8h).
// Uniform rotr<i>(fvh) gives fv[(nid-i)&15]; trr[i] = tr[n][(nid-i)&15];
// union over h,i = all 16 p exactly once. Cross-half merge gives full max M
// for tag n in all lanes (bit-exact: float max order-independent; candidate
// adds identical to reference). selrot8 supplies M[n^8] to the upper half.
__device__ __forceinline__ float step8(float fvh, const float* __restrict__ trr,
                                       bool hi, float fb) {
  float c0 = fvh          + trr[0];
  float c1 = rotr<1>(fvh) + trr[1];
  float c2 = rotr<2>(fvh) + trr[2];
  float c3 = rotr<3>(fvh) + trr[3];
  float c4 = rotr<4>(fvh) + trr[4];
  float c5 = rotr<5>(fvh) + trr[5];
  float c6 = rotr<6>(fvh) + trr[6];
  float c7 = rotr<7>(fvh) + trr[7];
  float a = fmaxf(fmaxf(c0, c1), c2);   // v_max3
  float b = fmaxf(fmaxf(c3, c4), c5);   // v_max3
  float w = fmaxf(c6, c7);
  float m = fmaxf(fmaxf(a, b), w);      // v_max3 (depth 2 after adds)
  float M = xhalf_max(m);               // full 16-way max for tag n, all lanes
  float base = selrot8(M, hi);          // lo: M[n], hi: M[n^8]
  return base + fb;                     // new fvh = nf[nid]
}

// ---------------------------------------------------------------------------
// K0: transpose feats [T,16] -> featsT [16, Tpad] so the chain can prefetch
// 4 steps per dwordx4. Throughput kernel (~25us), runs before the chain.
// ---------------------------------------------------------------------------
__global__ __launch_bounds__(256)
void k_tr(const float* __restrict__ feats, float* __restrict__ featsT,
          int T, int Tpad) {
  int t = blockIdx.x * blockDim.x + threadIdx.x;
  if (t >= T) return;
  const float4* fr = (const float4*)(feats + (size_t)t * 16);
  float4 a = fr[0], b = fr[1], c = fr[2], d = fr[3];
  featsT[ 0 * (size_t)Tpad + t] = a.x;
  featsT[ 1 * (size_t)Tpad + t] = a.y;
  featsT[ 2 * (size_t)Tpad + t] = a.z;
  featsT[ 3 * (size_t)Tpad + t] = a.w;
  featsT[ 4 * (size_t)Tpad + t] = b.x;
  featsT[ 5 * (size_t)Tpad + t] = b.y;
  featsT[ 6 * (size_t)Tpad + t] = b.z;
  featsT[ 7 * (size_t)Tpad + t] = b.w;
  featsT[ 8 * (size_t)Tpad + t] = c.x;
  featsT[ 9 * (size_t)Tpad + t] = c.y;
  featsT[10 * (size_t)Tpad + t] = c.z;
  featsT[11 * (size_t)Tpad + t] = c.w;
  featsT[12 * (size_t)Tpad + t] = d.x;
  featsT[13 * (size_t)Tpad + t] = d.y;
  featsT[14 * (size_t)Tpad + t] = d.z;
  featsT[15 * (size_t)Tpad + t] = d.w;
}

// ---------------------------------------------------------------------------
// K1: value-only exact Viterbi forward chain. ONE wave, r4 split-8 step.
// Feat prefetch from featsT: one dwordx4 per lane per 4 steps, imm offsets,
// single per-lane row base -> minimal non-chain issue in the hot loop.
// Stores a 64B checkpoint every CSZ steps; k_fv regenerates FV in parallel.
// ---------------------------------------------------------------------------
__global__ __launch_bounds__(64)
void k_chain(const float* __restrict__ featsT, const float* __restrict__ trans,
             float* __restrict__ CKPT, int* __restrict__ last_tag,
             int T, int Tpad) {
  const int l = threadIdx.x;
  const int n = l & 15;
  const bool hi = (l & 32) != 0;
  const int nid = n ^ (hi ? 8 : 0);

  float trr[8];
  #pragma unroll
  for (int i = 0; i < 8; ++i) trr[i] = trans[n * 16 + ((nid - i) & 15)];

  const float* __restrict__ frow = featsT + (size_t)nid * Tpad;

  float fvh = 0.0f; // fv[nid] = 0 initially

  const int Tm = (T >= 2 * PF) ? ((T - PF) & ~(PF - 1)) : 0;

  float4 f4[PF / 4];
  if (Tm > 0) {
    const float4* __restrict__ pi4 = (const float4*)frow;
    #pragma unroll
    for (int i = 0; i < PF / 4; ++i) f4[i] = pi4[i];
  }

  int t = 0;
  for (; t < Tm; t += PF) {
    if ((t & (CSZ - 1)) == 0) CKPT[(size_t)(t >> CSB) * 16 + nid] = fvh;
    const float4* __restrict__ pf4 = (const float4*)(frow + t + PF); // 16B-aligned
    #pragma unroll
    for (int q = 0; q < PF / 4; ++q) {
      float4 v = f4[q];
      fvh = step8(fvh, trr, hi, v.x);
      fvh = step8(fvh, trr, hi, v.y);
      fvh = step8(fvh, trr, hi, v.z);
      fvh = step8(fvh, trr, hi, v.w);
      f4[q] = pf4[q];   // prefetch steps t+PF+4q .. +3; never OOB (<= T-1)
    }
  }
  for (; t < T; ++t) { // tail (< 2*PF steps): scalar loads, cache-hot
    if ((t & (CSZ - 1)) == 0) CKPT[(size_t)(t >> CSB) * 16 + nid] = fvh;
    fvh = step8(fvh, trr, hi, frow[t]);
  }

  // last_tag = argmax of final fv (first-index tie-break, ascending p).
  // Lanes 0-15 (lo half) hold unshifted fv[n].
  float bv = __shfl(fvh, 0, 64); int bi = 0;
  #pragma unroll
  for (int p = 1; p < 16; ++p) {
    float ov = __shfl(fvh, p, 64);
    if (ov > bv) { bv = ov; bi = p; }
  }
  if (l == 0) *last_tag = bi;
}

// ---------------------------------------------------------------------------
// K1b: parallel FV regeneration. One wave per CSZ-step chunk; replays the
// identical fp32 recurrence from the chunk's checkpoint -> bit-exact FV.
// Reads ORIGINAL feats (FV output aliases the featsT buffer!).
// ---------------------------------------------------------------------------
__global__ __launch_bounds__(256)
void k_fv(const float* __restrict__ CKPT, const float* __restrict__ trans,
          const float* __restrict__ feats, float* __restrict__ FV, int T, int NC) {
  const int tid = threadIdx.x;
  const int wid = blockIdx.x * 4 + (tid >> 6);
  const int l = tid & 63;
  const int n = l & 15;
  if (wid >= NC) return;

  float trr[16];
  #pragma unroll
  for (int k = 0; k < 16; ++k) trr[k] = trans[n * 16 + ((n - k) & 15)];

  float fv = CKPT[(size_t)wid * 16 + n];
  const int a = wid * CSZ;
  int b = a + CSZ; if (b > T) b = T;
  for (int t = a; t < b; ++t) {
    FV[(size_t)t * 16 + n] = fv;            // FV[t] = fv entering step t
    fv = vstep(fv, trr) + feats[(size_t)t * 16 + n];
  }
}

// ---------------------------------------------------------------------------
// K2: parallel backpointer recompute. Thread per t.
// bp[t][n] = argmax_p fl(FV[t][p] + tr[n][p]), strict-> scan (first-max),
// bit-identical to the reference's jnp.argmax(scores, axis=1).
// ---------------------------------------------------------------------------
__global__ __launch_bounds__(256)
void k_bp(const float* __restrict__ FV, const float* __restrict__ trans,
          uint4* __restrict__ bp, int T) {
  __shared__ float str[256];
  const int tid = threadIdx.x;
  str[tid] = trans[tid];
  __syncthreads();
  const int t = blockIdx.x * blockDim.x + tid;
  if (t >= T) return;
  const float4* fr = (const float4*)(FV + (size_t)t * 16);
  float4 q0 = fr[0], q1 = fr[1], q2 = fr[2], q3 = fr[3];
  float fv[16] = {q0.x, q0.y, q0.z, q0.w, q1.x, q1.y, q1.z, q1.w,
                  q2.x, q2.y, q2.z, q2.w, q3.x, q3.y, q3.z, q3.w};
  uint32_t w[4];
  #pragma unroll
  for (int g = 0; g < 4; ++g) {
    uint32_t word = 0;
    #pragma unroll
    for (int s = 0; s < 4; ++s) {
      const int nn = 4 * g + s;
      float best = fv[0] + str[nn * 16 + 0];
      int bi = 0;
      #pragma unroll
      for (int p = 1; p < 16; ++p) {
        float v = fv[p] + str[nn * 16 + p];
        if (v > best) { best = v; bi = p; }
      }
      word |= (uint32_t)bi << (8 * s);
    }
    w[g] = word;
  }
  bp[t] = make_uint4(w[0], w[1], w[2], w[3]);
}

// ---------------------------------------------------------------------------
// K3: per-chunk 16-hypothesis backtrack (exact integer pointer chase).
// ---------------------------------------------------------------------------
__global__ __launch_bounds__(64)
void k_chase(const unsigned char* __restrict__ bp, unsigned char* __restrict__ st,
             unsigned char* __restrict__ maps, int T, int C) {
  const int tid = threadIdx.x;
  const int chunk = blockIdx.x * 4 + (tid >> 4);
  const int h = tid & 15;
  if (chunk >= C) return;
  const int a = chunk * L4;
  int b = a + L4; if (b > T) b = T;
  int cur = h;
  for (int t = b - 1; t >= a; --t) {
    cur = bp[(size_t)t * 16 + cur];
    st[(size_t)t * 16 + h] = (unsigned char)cur;
  }
  maps[chunk * 16 + h] = (unsigned char)cur;
}

// ---------------------------------------------------------------------------
// K4: compose GRP consecutive chunk maps into one super-map per group.
// ---------------------------------------------------------------------------
__global__ __launch_bounds__(64)
void k_group(const unsigned char* __restrict__ maps, unsigned char* __restrict__ sup,
             int C, int NG) {
  const int g = blockIdx.x;
  const int e = threadIdx.x;
  if (g >= NG || e >= 16) return;
  int hi = g * GRP + GRP - 1; if (hi > C - 1) hi = C - 1;
  int cur = e;
  for (int c = hi; c >= g * GRP; --c) cur = maps[c * 16 + cur];
  sup[g * 16 + e] = (unsigned char)cur;
}

// ---------------------------------------------------------------------------
// K5: resolve true tag at every chunk's end boundary.
// ---------------------------------------------------------------------------
__global__ __launch_bounds__(128)
void k_resolve(const unsigned char* __restrict__ maps, const unsigned char* __restrict__ sup,
               const int* __restrict__ last_tag, unsigned char* __restrict__ s_arr,
               int C, int NG) {
  __shared__ unsigned char Sg[4096];
  const int tid = threadIdx.x;
  if (tid == 0) {
    int cur = *last_tag;
    for (int g = NG - 1; g >= 0; --g) {
      Sg[g] = (unsigned char)cur;
      cur = sup[g * 16 + cur];
    }
  }
  __syncthreads();
  for (int g = tid; g < NG; g += blockDim.x) {
    int cur = Sg[g];
    int hi = g * GRP + GRP - 1; if (hi > C - 1) hi = C - 1;
    for (int c = hi; c >= g * GRP; --c) {
      s_arr[c] = (unsigned char)cur;
      cur = maps[c * 16 + cur];
    }
  }
}

// ---------------------------------------------------------------------------
// K6: emit out[t] = st[t*16 + s_arr[t / L4]] as int32.
// ---------------------------------------------------------------------------
__global__ void k_emit(const unsigned char* __restrict__ st,
                       const unsigned char* __restrict__ s_arr,
                       int* __restrict__ out, int T) {
  int t = blockIdx.x * blockDim.x + threadIdx.x;
  if (t < T) out[t] = (int)st[(size_t)t * 16 + s_arr[t / L4]];
}

extern "C" void kernel_launch(void* const* d_in, const int* in_sizes, int n_in,
                              void* d_out, int out_size, void* d_ws, size_t ws_size,
                              hipStream_t stream) {
  const float* feats = (const float*)d_in[0];   // [1, T, 16] fp32
  const float* trans = (const float*)d_in[1];   // [16, 16]  fp32
  int* out = (int*)d_out;                       // [T] int32

  const int T    = in_sizes[0] / 16;
  const int Tpad = (T + 3) & ~3;                // dwordx4-aligned rows
  const int C    = (T + L4 - 1) / L4;
  const int NG   = (C + GRP - 1) / GRP;
  const int NC   = (T + CSZ - 1) / CSZ;

  // featsT and FV SHARE one buffer (stream-ordered: k_tr writes featsT,
  // k_chain reads it, then k_fv overwrites the region with FV while reading
  // the ORIGINAL feats). Size = max of the two layouts.
  size_t fvt_len = (size_t)16 * (size_t)((Tpad > T + 1) ? Tpad : (T + 1));

  char* ws = (char*)d_ws;
  float* FVT          = (float*)ws;                          // featsT / FV
  float* CKPT         = FVT + fvt_len;                       // NC*16 floats
  unsigned char* bp   = (unsigned char*)(CKPT + (size_t)NC * 16); // T*16 B, 16B-aligned
  unsigned char* st   = bp + (size_t)T * 16;                 // T*16 B
  unsigned char* maps = st + (size_t)T * 16;                 // C*16
  unsigned char* sup  = maps + (size_t)C * 16;               // NG*16
  unsigned char* sarr = sup + (size_t)NG * 16;               // C
  int* last_tag = (int*)(((uintptr_t)(sarr + C) + 15) & ~(uintptr_t)15);
  size_t need = (size_t)((char*)(last_tag + 1) - ws);
  if (ws_size < need) return;  // insufficient scratch -> fail visibly

  k_tr<<<(T + 255) / 256, 256, 0, stream>>>(feats, FVT, T, Tpad);
  k_chain<<<1, 64, 0, stream>>>(FVT, trans, CKPT, last_tag, T, Tpad);
  k_fv<<<(NC + 3) / 4, 256, 0, stream>>>(CKPT, trans, feats, FVT, T, NC);
  k_bp<<<(T + 255) / 256, 256, 0, stream>>>(FVT, trans, (uint4*)bp, T);
  k_chase<<<(C + 3) / 4, 64, 0, stream>>>(bp, st, maps, T, C);
  k_group<<<NG, 64, 0, stream>>>(maps, sup, C, NG);
  k_resolve<<<1, 128, 0, stream>>>(maps, sup, last_tag, sarr, C, NG);
  const int thr = 256;
  k_emit<<<(T + thr - 1) / thr, thr, 0, stream>>>(st, sarr, out, T);
}

// Round 7
// 48528.323 us; speedup vs baseline: 1.6200x; 1.4155x over previous
//
#include <hip/hip_runtime.h>
#include <stdint.h>

#define L4   250   // chase chunk length
#define GRP  50    // chunks per map-composition group
#define PF   32    // feat prefetch depth in k_chain
#define CSZ  256   // checkpoint interval (power of 2)
#define CSB  8     // log2(CSZ)

// DPP row_ror:K — dst lane i reads src lane (i-K)&15 within its row of 16.
// Direction HW-validated bit-exact (absmax 0) in prior rounds.
template<int K>
__device__ __forceinline__ float rotr(float x) {
  return __int_as_float(__builtin_amdgcn_mov_dpp(__float_as_int(x), 0x120 + K, 0xF, 0xF, false));
}

// Full 16-candidate exact step (used by throughput kernel k_fv).
// Lane layout: n = lane&15, lane holds fv[n]; trr[k] = tr[n][(n-k)&15].
// fp32 max over 16 finite values is order-independent -> bit-identical to
// the reference's jnp.max regardless of tree shape.
__device__ __forceinline__ float vstep(float fv, const float* __restrict__ trr) {
  float c0  = fv           + trr[0];
  float c1  = rotr<1 >(fv) + trr[1];
  float c2  = rotr<2 >(fv) + trr[2];
  float c3  = rotr<3 >(fv) + trr[3];
  float c4  = rotr<4 >(fv) + trr[4];
  float c5  = rotr<5 >(fv) + trr[5];
  float c6  = rotr<6 >(fv) + trr[6];
  float c7  = rotr<7 >(fv) + trr[7];
  float c8  = rotr<8 >(fv) + trr[8];
  float c9  = rotr<9 >(fv) + trr[9];
  float c10 = rotr<10>(fv) + trr[10];
  float c11 = rotr<11>(fv) + trr[11];
  float c12 = rotr<12>(fv) + trr[12];
  float c13 = rotr<13>(fv) + trr[13];
  float c14 = rotr<14>(fv) + trr[14];
  float c15 = rotr<15>(fv) + trr[15];
  float t0 = fmaxf(fmaxf(c0,  c1),  c2);
  float t1 = fmaxf(fmaxf(c3,  c4),  c5);
  float t2 = fmaxf(fmaxf(c6,  c7),  c8);
  float t3 = fmaxf(fmaxf(c9,  c10), c11);
  float t4 = fmaxf(fmaxf(c12, c13), c14);
  float u0 = fmaxf(fmaxf(t0, t1), t2);
  float u1 = fmaxf(fmaxf(t3, t4), c15);
  return fmaxf(u0, u1);
}

// Split 8-candidate exact step — FULL INLINE ASM, forced schedule.
// Math bit-identical to r4's HW-validated step8 (absmax 0):
//   lane (h,n) holds fvh = fv[nid], nid = n ^ (8h);
//   c_i = row_ror:i(fvh) + trr[i] = fv[(nid-i)&15] + tr[n][(nid-i)&15];
//   union over h,i = all 16 p exactly once; 16-way fp32 max is
//   order-independent; permlane32_swap merges halves (pairing-agnostic
//   (m,m) trick); masked row_ror:8 (row_mask 0xC) redistributes M[n^8]
//   to the upper half; + feat.
// Forced: 7x v_add_f32_dpp (no separate movs), v_max3 tree, hand-placed
// s_nop for the VALU-write -> DPP-read hazard (2 wait states), self-
// contained at block boundaries (first DPP read is >= 2 slots in).
__device__ __forceinline__ float step8_asm(float fvh,
    float t0, float t1, float t2, float t3,
    float t4, float t5, float t6, float t7, float fb) {
  float c0, c1, c2, c3, c4, c5, c6, c7, a, b, w, m, mc, M;
  asm volatile(
    "v_add_f32 %[c0], %[fv], %[t0]\n\t"
    "s_nop 0\n\t"
    "v_add_f32_dpp %[c1], %[fv], %[t1] row_ror:1 row_mask:0xf bank_mask:0xf\n\t"
    "v_add_f32_dpp %[c2], %[fv], %[t2] row_ror:2 row_mask:0xf bank_mask:0xf\n\t"
    "v_add_f32_dpp %[c3], %[fv], %[t3] row_ror:3 row_mask:0xf bank_mask:0xf\n\t"
    "v_add_f32_dpp %[c4], %[fv], %[t4] row_ror:4 row_mask:0xf bank_mask:0xf\n\t"
    "v_add_f32_dpp %[c5], %[fv], %[t5] row_ror:5 row_mask:0xf bank_mask:0xf\n\t"
    "v_add_f32_dpp %[c6], %[fv], %[t6] row_ror:6 row_mask:0xf bank_mask:0xf\n\t"
    "v_add_f32_dpp %[c7], %[fv], %[t7] row_ror:7 row_mask:0xf bank_mask:0xf\n\t"
    "v_max3_f32 %[a], %[c0], %[c1], %[c2]\n\t"
    "v_max3_f32 %[b], %[c3], %[c4], %[c5]\n\t"
    "v_max_f32 %[w], %[c6], %[c7]\n\t"
    "v_max3_f32 %[m], %[a], %[b], %[w]\n\t"
    "v_mov_b32 %[mc], %[m]\n\t"
    "s_nop 1\n\t"
    "v_permlane32_swap_b32 %[m], %[mc]\n\t"
    "v_max_f32 %[M], %[m], %[mc]\n\t"
    "s_nop 1\n\t"
    "v_mov_b32_dpp %[M], %[M] row_ror:8 row_mask:0xc bank_mask:0xf\n\t"
    "v_add_f32 %[fv], %[M], %[fb]\n\t"
    : [fv]"+v"(fvh),
      [c0]"=&v"(c0), [c1]"=&v"(c1), [c2]"=&v"(c2), [c3]"=&v"(c3),
      [c4]"=&v"(c4), [c5]"=&v"(c5), [c6]"=&v"(c6), [c7]"=&v"(c7),
      [a]"=&v"(a), [b]"=&v"(b), [w]"=&v"(w), [m]"=&v"(m),
      [mc]"=&v"(mc), [M]"=&v"(M)
    : [t0]"v"(t0), [t1]"v"(t1), [t2]"v"(t2), [t3]"v"(t3),
      [t4]"v"(t4), [t5]"v"(t5), [t6]"v"(t6), [t7]"v"(t7), [fb]"v"(fb));
  return fvh;
}

// ---------------------------------------------------------------------------
// K1: value-only exact Viterbi forward chain. ONE wave, r4 structure
// (best measured: 142 cy/step) with the step forced into scheduled asm.
// Scalar imm-offset prefetch (r6's dwordx4-transpose regressed; reverted).
// Stores a 64B checkpoint every CSZ steps; k_fv regenerates FV in parallel.
// ---------------------------------------------------------------------------
__global__ __launch_bounds__(64)
void k_chain(const float* __restrict__ feats, const float* __restrict__ trans,
             float* __restrict__ CKPT, int* __restrict__ last_tag, int T) {
  const int l = threadIdx.x;
  const int n = l & 15;
  const bool hi = (l & 32) != 0;
  const int nid = n ^ (hi ? 8 : 0);

  float tr0 = trans[n * 16 + ((nid - 0) & 15)];
  float tr1 = trans[n * 16 + ((nid - 1) & 15)];
  float tr2 = trans[n * 16 + ((nid - 2) & 15)];
  float tr3 = trans[n * 16 + ((nid - 3) & 15)];
  float tr4 = trans[n * 16 + ((nid - 4) & 15)];
  float tr5 = trans[n * 16 + ((nid - 5) & 15)];
  float tr6 = trans[n * 16 + ((nid - 6) & 15)];
  float tr7 = trans[n * 16 + ((nid - 7) & 15)];

  float fvh = 0.0f; // fv[nid] = 0 initially

  float fbuf[PF];
  #pragma unroll
  for (int i = 0; i < PF; ++i) {
    int idx = i < T ? i : (T - 1);
    fbuf[i] = feats[(size_t)idx * 16 + nid];
  }

  int t = 0;
  const int Tm = (T >= 2 * PF) ? ((T - PF) & ~(PF - 1)) : 0;
  for (; t < Tm; t += PF) {
    if ((t & (CSZ - 1)) == 0) CKPT[(size_t)(t >> CSB) * 16 + nid] = fvh;
    const float* __restrict__ pf_ptr = feats + (size_t)(t + PF) * 16; // uniform
    #pragma unroll
    for (int u = 0; u < PF; ++u) {
      fvh = step8_asm(fvh, tr0, tr1, tr2, tr3, tr4, tr5, tr6, tr7, fbuf[u]);
      fbuf[u] = pf_ptr[u * 16 + nid];   // imm-offset load, never OOB (t+u+PF <= T-1)
    }
  }
  for (; t < T; ++t) { // tail (< 2*PF steps): direct loads, cache-hot
    if ((t & (CSZ - 1)) == 0) CKPT[(size_t)(t >> CSB) * 16 + nid] = fvh;
    fvh = step8_asm(fvh, tr0, tr1, tr2, tr3, tr4, tr5, tr6, tr7,
                    feats[(size_t)t * 16 + nid]);
  }

  // last_tag = argmax of final fv (first-index tie-break, ascending p).
  // Lanes 0-15 (lo half) hold unshifted fv[n].
  float bv = __shfl(fvh, 0, 64); int bi = 0;
  #pragma unroll
  for (int p = 1; p < 16; ++p) {
    float ov = __shfl(fvh, p, 64);
    if (ov > bv) { bv = ov; bi = p; }
  }
  if (l == 0) *last_tag = bi;
}

// ---------------------------------------------------------------------------
// K1b: parallel FV regeneration. One wave per CSZ-step chunk; replays the
// identical fp32 recurrence from the chunk's checkpoint -> bit-exact FV.
// Throughput-bound (thousands of independent waves).
// ---------------------------------------------------------------------------
__global__ __launch_bounds__(256)
void k_fv(const float* __restrict__ CKPT, const float* __restrict__ trans,
          const float* __restrict__ feats, float* __restrict__ FV, int T, int NC) {
  const int tid = threadIdx.x;
  const int wid = blockIdx.x * 4 + (tid >> 6);
  const int l = tid & 63;
  const int n = l & 15;
  if (wid >= NC) return;

  float trr[16];
  #pragma unroll
  for (int k = 0; k < 16; ++k) trr[k] = trans[n * 16 + ((n - k) & 15)];

  float fv = CKPT[(size_t)wid * 16 + n];
  const int a = wid * CSZ;
  int b = a + CSZ; if (b > T) b = T;
  for (int t = a; t < b; ++t) {
    FV[(size_t)t * 16 + n] = fv;            // FV[t] = fv entering step t
    fv = vstep(fv, trr) + feats[(size_t)t * 16 + n];
  }
}

// ---------------------------------------------------------------------------
// K2: parallel backpointer recompute. Thread per t.
// bp[t][n] = argmax_p fl(FV[t][p] + tr[n][p]), strict-> scan (first-max),
// bit-identical to the reference's jnp.argmax(scores, axis=1).
// ---------------------------------------------------------------------------
__global__ __launch_bounds__(256)
void k_bp(const float* __restrict__ FV, const float* __restrict__ trans,
          uint4* __restrict__ bp, int T) {
  __shared__ float str[256];
  const int tid = threadIdx.x;
  str[tid] = trans[tid];
  __syncthreads();
  const int t = blockIdx.x * blockDim.x + tid;
  if (t >= T) return;
  const float4* fr = (const float4*)(FV + (size_t)t * 16);
  float4 q0 = fr[0], q1 = fr[1], q2 = fr[2], q3 = fr[3];
  float fv[16] = {q0.x, q0.y, q0.z, q0.w, q1.x, q1.y, q1.z, q1.w,
                  q2.x, q2.y, q2.z, q2.w, q3.x, q3.y, q3.z, q3.w};
  uint32_t w[4];
  #pragma unroll
  for (int g = 0; g < 4; ++g) {
    uint32_t word = 0;
    #pragma unroll
    for (int s = 0; s < 4; ++s) {
      const int nn = 4 * g + s;
      float best = fv[0] + str[nn * 16 + 0];
      int bi = 0;
      #pragma unroll
      for (int p = 1; p < 16; ++p) {
        float v = fv[p] + str[nn * 16 + p];
        if (v > best) { best = v; bi = p; }
      }
      word |= (uint32_t)bi << (8 * s);
    }
    w[g] = word;
  }
  bp[t] = make_uint4(w[0], w[1], w[2], w[3]);
}

// ---------------------------------------------------------------------------
// K3: per-chunk 16-hypothesis backtrack (exact integer pointer chase).
// ---------------------------------------------------------------------------
__global__ __launch_bounds__(64)
void k_chase(const unsigned char* __restrict__ bp, unsigned char* __restrict__ st,
             unsigned char* __restrict__ maps, int T, int C) {
  const int tid = threadIdx.x;
  const int chunk = blockIdx.x * 4 + (tid >> 4);
  const int h = tid & 15;
  if (chunk >= C) return;
  const int a = chunk * L4;
  int b = a + L4; if (b > T) b = T;
  int cur = h;
  for (int t = b - 1; t >= a; --t) {
    cur = bp[(size_t)t * 16 + cur];
    st[(size_t)t * 16 + h] = (unsigned char)cur;
  }
  maps[chunk * 16 + h] = (unsigned char)cur;
}

// ---------------------------------------------------------------------------
// K4: compose GRP consecutive chunk maps into one super-map per group.
// ---------------------------------------------------------------------------
__global__ __launch_bounds__(64)
void k_group(const unsigned char* __restrict__ maps, unsigned char* __restrict__ sup,
             int C, int NG) {
  const int g = blockIdx.x;
  const int e = threadIdx.x;
  if (g >= NG || e >= 16) return;
  int hi = g * GRP + GRP - 1; if (hi > C - 1) hi = C - 1;
  int cur = e;
  for (int c = hi; c >= g * GRP; --c) cur = maps[c * 16 + cur];
  sup[g * 16 + e] = (unsigned char)cur;
}

// ---------------------------------------------------------------------------
// K5: resolve true tag at every chunk's end boundary.
// ---------------------------------------------------------------------------
__global__ __launch_bounds__(128)
void k_resolve(const unsigned char* __restrict__ maps, const unsigned char* __restrict__ sup,
               const int* __restrict__ last_tag, unsigned char* __restrict__ s_arr,
               int C, int NG) {
  __shared__ unsigned char Sg[4096];
  const int tid = threadIdx.x;
  if (tid == 0) {
    int cur = *last_tag;
    for (int g = NG - 1; g >= 0; --g) {
      Sg[g] = (unsigned char)cur;
      cur = sup[g * 16 + cur];
    }
  }
  __syncthreads();
  for (int g = tid; g < NG; g += blockDim.x) {
    int cur = Sg[g];
    int hi = g * GRP + GRP - 1; if (hi > C - 1) hi = C - 1;
    for (int c = hi; c >= g * GRP; --c) {
      s_arr[c] = (unsigned char)cur;
      cur = maps[c * 16 + cur];
    }
  }
}

// ---------------------------------------------------------------------------
// K6: emit out[t] = st[t*16 + s_arr[t / L4]] as int32.
// ---------------------------------------------------------------------------
__global__ void k_emit(const unsigned char* __restrict__ st,
                       const unsigned char* __restrict__ s_arr,
                       int* __restrict__ out, int T) {
  int t = blockIdx.x * blockDim.x + threadIdx.x;
  if (t < T) out[t] = (int)st[(size_t)t * 16 + s_arr[t / L4]];
}

extern "C" void kernel_launch(void* const* d_in, const int* in_sizes, int n_in,
                              void* d_out, int out_size, void* d_ws, size_t ws_size,
                              hipStream_t stream) {
  const float* feats = (const float*)d_in[0];   // [1, T, 16] fp32
  const float* trans = (const float*)d_in[1];   // [16, 16]  fp32
  int* out = (int*)d_out;                       // [T] int32

  const int T  = in_sizes[0] / 16;
  const int C  = (T + L4 - 1) / L4;
  const int NG = (C + GRP - 1) / GRP;
  const int NC = (T + CSZ - 1) / CSZ;

  char* ws = (char*)d_ws;
  float* FV           = (float*)ws;                           // (T+1)*16 floats
  float* CKPT         = FV + (size_t)(T + 1) * 16;            // NC*16 floats
  unsigned char* bp   = (unsigned char*)(CKPT + (size_t)NC * 16); // T*16 B, 16B-aligned
  unsigned char* st   = bp + (size_t)T * 16;                  // T*16 B
  unsigned char* maps = st + (size_t)T * 16;                  // C*16
  unsigned char* sup  = maps + (size_t)C * 16;                // NG*16
  unsigned char* sarr = sup + (size_t)NG * 16;                // C
  int* last_tag = (int*)(((uintptr_t)(sarr + C) + 15) & ~(uintptr_t)15);
  size_t need = (size_t)((char*)(last_tag + 1) - ws);
  if (ws_size < need) return;  // insufficient scratch -> fail visibly

  k_chain<<<1, 64, 0, stream>>>(feats, trans, CKPT, last_tag, T);
  k_fv<<<(NC + 3) / 4, 256, 0, stream>>>(CKPT, trans, feats, FV, T, NC);
  k_bp<<<(T + 255) / 256, 256, 0, stream>>>(FV, trans, (uint4*)bp, T);
  k_chase<<<(C + 3) / 4, 64, 0, stream>>>(bp, st, maps, T, C);
  k_group<<<NG, 64, 0, stream>>>(maps, sup, C, NG);
  k_resolve<<<1, 128, 0, stream>>>(maps, sup, last_tag, sarr, C, NG);
  const int thr = 256;
  k_emit<<<(T + thr - 1) / thr, thr, 0, stream>>>(st, sarr, out, T);
}